// Round 1
// baseline (792.927 us; speedup 1.0000x reference)
//
#include <hip/hip_runtime.h>
#include <math.h>

#define cB 4
#define cT 2048
#define cD 1024
#define cE 6
#define cP 36
#define cDA 512
#define SCALE 0.03125f
#define LN_EPS 1e-5f
#define THRESH 0.3f

// workspace offsets (in floats)
#define OFF_QK      0          // E*D            = 6144
#define OFF_COEFF   6144       // E*B*T          = 49152
#define OFF_XBAR    55296      // E*B*D          = 24576
#define OFF_FORM    79872      // E*B*D          = 24576
#define OFF_C       104448     // P*B*2DA        = 147456
#define OFF_H       251904     // P*B*DA         = 73728
#define OFF_HS      325632     // P*B*D          = 147456
#define OFF_INS     473088     // P*B*D          = 147456
#define OFF_STR     620544     // P*B            = 144
#define OFF_MASK    620688     // P              = 36
#define OFF_CNT     620724     // [flag, inv_count]
#define OFF_NORMED  620728     // B*D            = 4096
#define OFF_ADD     624824     // B*D            = 4096 (16B aligned)

__device__ __forceinline__ float gelu_f(float x){
  return 0.5f * x * (1.f + erff(x * 0.70710678118654752440f));
}

// init accumulation buffers with their biases (ws re-poisoned each call)
__global__ void k_init(float* __restrict__ ws,
                       const float* __restrict__ bv, const float* __restrict__ ba,
                       const float* __restrict__ bb, const float* __restrict__ b1,
                       const float* __restrict__ bs1, const float* __restrict__ bs2,
                       const float* __restrict__ outb){
  int i = blockIdx.x * 256 + threadIdx.x;
  if (i < 24576){ ws[OFF_XBAR + i] = 0.f; return; }
  i -= 24576;
  if (i < 24576){ int f = i & 1023; int e = i >> 12; ws[OFF_FORM + i] = bv[e*cD + f]; return; }
  i -= 24576;
  if (i < 147456){ int j = i & 1023; int p = i >> 12;
    ws[OFF_C + i] = (j < cDA) ? ba[p*cDA + j] : bb[p*cDA + j - cDA]; return; }
  i -= 147456;
  if (i < 73728){ int j = i & 511; int p = i >> 11; ws[OFF_H + i] = b1[p*cDA + j]; return; }
  i -= 73728;
  if (i < 147456){ int j = i & 1023; int p = i >> 12; ws[OFF_HS + i] = bs1[p*cD + j]; return; }
  i -= 147456;
  if (i < 147456){ int j = i & 1023; int p = i >> 12; ws[OFF_INS + i] = bs2[p*cD + j]; return; }
  i -= 147456;
  if (i < 4096){ ws[OFF_ADD + i] = outb[i & 1023]; return; }
}

// qk_eff[e,d] = sum_f Wk[e,d,f] * q[e,f]   (one wave per (e,d) row)
__global__ void k_qk(const float* __restrict__ Wk, const float* __restrict__ q,
                     float* __restrict__ qk){
  int wid = (blockIdx.x * 256 + threadIdx.x) >> 6;
  int lane = threadIdx.x & 63;
  if (wid >= cE * cD) return;
  int e = wid >> 10;
  const float4* wrow = (const float4*)(Wk + (size_t)wid * cD);
  const float4* qrow = (const float4*)(q + e * cD);
  float acc = 0.f;
  #pragma unroll
  for (int it = 0; it < 4; ++it){
    float4 w4 = wrow[it*64 + lane];
    float4 q4 = qrow[it*64 + lane];
    acc += w4.x*q4.x + w4.y*q4.y + w4.z*q4.z + w4.w*q4.w;
  }
  for (int off = 32; off; off >>= 1) acc += __shfl_down(acc, off);
  if (lane == 0) qk[wid] = acc;
}

// logits[e,b,t] = scale * w[b,t,e] * dot(eo[e,b,t,:], qk_eff[e,:])  (one wave per row)
__global__ void k_logits(const float* __restrict__ eo, const float* __restrict__ ew,
                         const float* __restrict__ qk, float* __restrict__ coeff){
  int wid = (blockIdx.x * 256 + threadIdx.x) >> 6;
  int lane = threadIdx.x & 63;
  int e = wid / (cB * cT);
  int bt = wid % (cB * cT);
  const float4* row = (const float4*)(eo + (size_t)wid * cD);
  const float4* q4p = (const float4*)(qk + e * cD);
  float acc = 0.f;
  #pragma unroll
  for (int it = 0; it < 4; ++it){
    float4 a = row[it*64 + lane];
    float4 b = q4p[it*64 + lane];
    acc += a.x*b.x + a.y*b.y + a.z*b.z + a.w*b.w;
  }
  for (int off = 32; off; off >>= 1) acc += __shfl_down(acc, off);
  if (lane == 0){
    int b = bt / cT, t = bt % cT;
    coeff[wid] = acc * ew[(b*cT + t)*cE + e] * SCALE;
  }
}

// per (e,b): softmax over T, then fold in w[b,t,e] for the xbar pass
__global__ void k_softmax(float* __restrict__ coeff, const float* __restrict__ ew){
  int eb = blockIdx.x; int e = eb / cB, b = eb % cB;
  float* row = coeff + (size_t)eb * cT;
  __shared__ float red[256];
  int tid = threadIdx.x;
  float v[8]; float m = -INFINITY;
  #pragma unroll
  for (int k = 0; k < 8; ++k){ v[k] = row[tid + k*256]; m = fmaxf(m, v[k]); }
  red[tid] = m; __syncthreads();
  for (int s = 128; s; s >>= 1){ if (tid < s) red[tid] = fmaxf(red[tid], red[tid+s]); __syncthreads(); }
  m = red[0]; __syncthreads();
  float sum = 0.f;
  #pragma unroll
  for (int k = 0; k < 8; ++k){ v[k] = expf(v[k] - m); sum += v[k]; }
  red[tid] = sum; __syncthreads();
  for (int s = 128; s; s >>= 1){ if (tid < s) red[tid] += red[tid+s]; __syncthreads(); }
  float inv = 1.f / red[0];
  #pragma unroll
  for (int k = 0; k < 8; ++k){
    int t = tid + k*256;
    row[t] = v[k] * inv * ew[(b*cT + t)*cE + e];
  }
}

// xbar[e,b,d] += sum_{t in seg} coeff[e,b,t] * eo[e,b,t,d]
__global__ void k_xbar(const float* __restrict__ eo, const float* __restrict__ coeff,
                       float* __restrict__ xbar){
  int bid = blockIdx.x;
  int seg = bid & 7;  bid >>= 3;
  int dch = bid & 3;  bid >>= 2;
  int b   = bid & 3;  bid >>= 2;
  int e   = bid;
  int tid = threadIdx.x;
  int eb = e * cB + b;
  __shared__ float sc[256];
  sc[tid] = coeff[(size_t)eb*cT + seg*256 + tid];
  __syncthreads();
  const float* base = eo + ((size_t)eb*cT + seg*256)*cD + dch*256 + tid;
  float acc = 0.f;
  #pragma unroll 4
  for (int tt = 0; tt < 256; ++tt) acc += sc[tt] * base[(size_t)tt * cD];
  atomicAdd(&xbar[eb*cD + dch*256 + tid], acc);
}

// formulas[e,b,f] += sum_{d in chunk} xbar[e,b,d] * Wv[e,d,f]
__global__ void k_formulas(const float* __restrict__ Wv, const float* __restrict__ xbar,
                           float* __restrict__ form){
  int bid = blockIdx.x;
  int dch = bid & 7; bid >>= 3;
  int fch = bid & 3; bid >>= 2;
  int e = bid;
  int tid = threadIdx.x;
  __shared__ float4 xl[128];
  if (tid < 128){
    float4 v;
    v.x = xbar[(e*cB+0)*cD + dch*128 + tid];
    v.y = xbar[(e*cB+1)*cD + dch*128 + tid];
    v.z = xbar[(e*cB+2)*cD + dch*128 + tid];
    v.w = xbar[(e*cB+3)*cD + dch*128 + tid];
    xl[tid] = v;
  }
  __syncthreads();
  float a0=0,a1=0,a2=0,a3=0;
  const float* wbase = Wv + (size_t)e*cD*cD + (size_t)(dch*128)*cD + fch*256 + tid;
  #pragma unroll 8
  for (int dd = 0; dd < 128; ++dd){
    float w = wbase[(size_t)dd * cD];
    float4 x = xl[dd];
    a0 += x.x*w; a1 += x.y*w; a2 += x.z*w; a3 += x.w*w;
  }
  int o = fch*256 + tid;
  atomicAdd(&form[(e*cB+0)*cD + o], a0);
  atomicAdd(&form[(e*cB+1)*cD + o], a1);
  atomicAdd(&form[(e*cB+2)*cD + o], a2);
  atomicAdd(&form[(e*cB+3)*cD + o], a3);
}

// generic 4-row GEMV: out[p,b,colOff+c] += sum_{d chunk} act(in[p,b,d]) * W[p,d,c]
// gatherMode: 0 = in is (P,B,Din); 1 = formulas[p/6]; 2 = formulas[p%6]
__global__ void k_gemv(const float* __restrict__ in, const float* __restrict__ W,
                       float* __restrict__ out, const float* __restrict__ form,
                       int Din, int Dout, int nC, int outStride, int colOff,
                       int gatherMode, int actGelu){
  int nD = Din >> 8;
  int bid = blockIdx.x;
  int dch = bid % nD; bid /= nD;
  int cch = bid % nC; bid /= nC;
  int p = bid;
  int tid = threadIdx.x;
  __shared__ float4 il[256];
  const float* inbase;
  if (gatherMode){
    int e = (gatherMode == 1) ? (p / cE) : (p % cE);
    inbase = form + (size_t)e * cB * cD;
  } else {
    inbase = in + (size_t)p * cB * Din;
  }
  int d0 = dch << 8;
  {
    float4 v;
    v.x = inbase[0*Din + d0 + tid];
    v.y = inbase[1*Din + d0 + tid];
    v.z = inbase[2*Din + d0 + tid];
    v.w = inbase[3*Din + d0 + tid];
    if (actGelu){ v.x = gelu_f(v.x); v.y = gelu_f(v.y); v.z = gelu_f(v.z); v.w = gelu_f(v.w); }
    il[tid] = v;
  }
  __syncthreads();
  float a0=0,a1=0,a2=0,a3=0;
  const float* wbase = W + (size_t)p*Din*Dout + (size_t)d0*Dout + (cch<<8) + tid;
  #pragma unroll 8
  for (int dd = 0; dd < 256; ++dd){
    float w = wbase[(size_t)dd * Dout];
    float4 x = il[dd];
    a0 += x.x*w; a1 += x.y*w; a2 += x.z*w; a3 += x.w*w;
  }
  size_t ob = (size_t)p*cB*outStride + colOff + (cch<<8) + tid;
  atomicAdd(&out[ob],                 a0);
  atomicAdd(&out[ob +   outStride],   a1);
  atomicAdd(&out[ob + 2*outStride],   a2);
  atomicAdd(&out[ob + 3*outStride],   a3);
}

// strength[p,b] = sigmoid(dot(gelu(pre_h[p,b,:]), W2[p,:]) + b2[p])  (one wave per (p,b))
__global__ void k_strength(const float* __restrict__ pre_h, const float* __restrict__ W2,
                           const float* __restrict__ b2, float* __restrict__ str){
  int p = blockIdx.x;
  int b = threadIdx.x >> 6;
  int lane = threadIdx.x & 63;
  const float* h = pre_h + (size_t)(p*cB + b)*cDA;
  const float* w = W2 + (size_t)p*cDA;
  float acc = 0.f;
  #pragma unroll
  for (int it = 0; it < 8; ++it){
    int j = it*64 + lane;
    acc += gelu_f(h[j]) * w[j];
  }
  for (int off = 32; off; off >>= 1) acc += __shfl_down(acc, off);
  if (lane == 0) str[p*cB + b] = 1.f / (1.f + expf(-(acc + b2[p])));
}

// avg strength per pair, mask, active count; writes outputs 1 & 2
__global__ void k_combine(const float* __restrict__ str, float* __restrict__ ws,
                          float* __restrict__ out_tail){
  int tid = threadIdx.x;
  __shared__ float mk[64];
  float msk = 0.f;
  if (tid < cP){
    float avg = 0.25f * (str[tid*4] + str[tid*4+1] + str[tid*4+2] + str[tid*4+3]);
    out_tail[tid] = avg;
    msk = (avg > THRESH) ? 1.f : 0.f;
    ws[OFF_MASK + tid] = msk;
  }
  mk[tid] = msk;
  __syncthreads();
  if (tid == 0){
    float cnt = 0.f;
    for (int i = 0; i < cP; ++i) cnt += mk[i];
    out_tail[cP] = cnt;
    ws[OFF_CNT]     = (cnt > 0.f) ? 1.f : 0.f;
    ws[OFF_CNT + 1] = 1.f / fmaxf(cnt, 1.f);
  }
}

// total[b,:] = sum_p mask*strength*pair_gate*inv_cnt * insight_pre[p,b,:]; then LayerNorm
__global__ void k_totln(const float* __restrict__ ins, const float* __restrict__ str,
                        const float* __restrict__ mask, const float* __restrict__ pg,
                        const float* __restrict__ cnt2, const float* __restrict__ gamma,
                        const float* __restrict__ beta, float* __restrict__ normed){
  int b = blockIdx.x;
  int tid = threadIdx.x;
  __shared__ float sc[cP];
  __shared__ float red[256];
  if (tid < cP) sc[tid] = mask[tid] * str[tid*4 + b] * pg[tid] * cnt2[1];
  __syncthreads();
  float tot[4];
  #pragma unroll
  for (int k = 0; k < 4; ++k){
    int d = tid + k*256;
    float s = 0.f;
    for (int p = 0; p < cP; ++p) s += sc[p] * ins[(size_t)(p*cB + b)*cD + d];
    tot[k] = s;
  }
  float lsum = tot[0] + tot[1] + tot[2] + tot[3];
  red[tid] = lsum; __syncthreads();
  for (int s = 128; s; s >>= 1){ if (tid < s) red[tid] += red[tid+s]; __syncthreads(); }
  float mu = red[0] * (1.f / cD); __syncthreads();
  float q = 0.f;
  #pragma unroll
  for (int k = 0; k < 4; ++k){ float dxy = tot[k] - mu; q += dxy*dxy; }
  red[tid] = q; __syncthreads();
  for (int s = 128; s; s >>= 1){ if (tid < s) red[tid] += red[tid+s]; __syncthreads(); }
  float rs = rsqrtf(red[0] * (1.f / cD) + LN_EPS);
  #pragma unroll
  for (int k = 0; k < 4; ++k){
    int d = tid + k*256;
    normed[b*cD + d] = (tot[k] - mu) * rs * gamma[d] + beta[d];
  }
}

// add_pre[b,f] += sum_{d chunk} normed[b,d] * out_W[d,f]
__global__ void k_proj(const float* __restrict__ normed, const float* __restrict__ W,
                       float* __restrict__ addp){
  int bid = blockIdx.x;
  int dch = bid & 7; int fch = bid >> 3;
  int tid = threadIdx.x;
  __shared__ float4 nl[128];
  if (tid < 128){
    float4 v;
    v.x = normed[0*cD + dch*128 + tid];
    v.y = normed[1*cD + dch*128 + tid];
    v.z = normed[2*cD + dch*128 + tid];
    v.w = normed[3*cD + dch*128 + tid];
    nl[tid] = v;
  }
  __syncthreads();
  float a0=0,a1=0,a2=0,a3=0;
  const float* wbase = W + (size_t)(dch*128)*cD + fch*256 + tid;
  #pragma unroll 8
  for (int dd = 0; dd < 128; ++dd){
    float w = wbase[(size_t)dd * cD];
    float4 x = nl[dd];
    a0 += x.x*w; a1 += x.y*w; a2 += x.z*w; a3 += x.w*w;
  }
  int o = fch*256 + tid;
  atomicAdd(&addp[0*cD + o], a0);
  atomicAdd(&addp[1*cD + o], a1);
  atomicAdd(&addp[2*cD + o], a2);
  atomicAdd(&addp[3*cD + o], a3);
}

// out[b,t,:] = bridge[b,t,:] + flag * analogy_gate * add_pre[b,:]
__global__ void k_final(const float* __restrict__ bridge, const float* __restrict__ addp,
                        const float* __restrict__ cnt2, const float* __restrict__ gate,
                        float* __restrict__ out){
  float g = gate[0] * cnt2[0];
  const float4* b4 = (const float4*)bridge;
  const float4* a4 = (const float4*)addp;
  float4* o4 = (float4*)out;
  int total4 = cB*cT*cD/4;
  for (int i = blockIdx.x*256 + threadIdx.x; i < total4; i += gridDim.x*256){
    float4 bb = b4[i];
    int b = i >> 19;            // i / (T*D/4)
    float4 aa = a4[b*256 + (i & 255)];
    bb.x += g*aa.x; bb.y += g*aa.y; bb.z += g*aa.z; bb.w += g*aa.w;
    o4[i] = bb;
  }
}

extern "C" void kernel_launch(void* const* d_in, const int* in_sizes, int n_in,
                              void* d_out, int out_size, void* d_ws, size_t ws_size,
                              hipStream_t stream) {
  const float* bridge = (const float*)d_in[0];
  const float* eo     = (const float*)d_in[1];
  const float* ew     = (const float*)d_in[2];
  const float* q      = (const float*)d_in[3];
  const float* Wk     = (const float*)d_in[4];
  /* cond_bk (d_in[5]) is softmax-invariant — unused */
  const float* Wv     = (const float*)d_in[6];
  const float* bv     = (const float*)d_in[7];
  const float* Wa     = (const float*)d_in[8];
  const float* ba     = (const float*)d_in[9];
  const float* Wb     = (const float*)d_in[10];
  const float* bb     = (const float*)d_in[11];
  const float* W1     = (const float*)d_in[12];
  const float* b1     = (const float*)d_in[13];
  const float* W2     = (const float*)d_in[14];
  const float* b2     = (const float*)d_in[15];
  const float* Ws1    = (const float*)d_in[16];
  const float* bs1    = (const float*)d_in[17];
  const float* Ws2    = (const float*)d_in[18];
  const float* bs2    = (const float*)d_in[19];
  const float* pg     = (const float*)d_in[20];
  const float* gamma  = (const float*)d_in[21];
  const float* beta   = (const float*)d_in[22];
  const float* outW   = (const float*)d_in[23];
  const float* outb   = (const float*)d_in[24];
  const float* agate  = (const float*)d_in[25];
  float* out = (float*)d_out;
  float* ws  = (float*)d_ws;

  k_init<<<2224, 256, 0, stream>>>(ws, bv, ba, bb, b1, bs1, bs2, outb);
  k_qk<<<1536, 256, 0, stream>>>(Wk, q, ws + OFF_QK);
  k_logits<<<12288, 256, 0, stream>>>(eo, ew, ws + OFF_QK, ws + OFF_COEFF);
  k_softmax<<<24, 256, 0, stream>>>(ws + OFF_COEFF, ew);
  k_xbar<<<768, 256, 0, stream>>>(eo, ws + OFF_COEFF, ws + OFF_XBAR);
  k_formulas<<<192, 256, 0, stream>>>(Wv, ws + OFF_XBAR, ws + OFF_FORM);
  // pair stages: a, b -> c
  k_gemv<<<288, 256, 0, stream>>>(nullptr, Wa, ws + OFF_C, ws + OFF_FORM,
                                  1024, 512, 2, 1024, 0,   1, 0);
  k_gemv<<<288, 256, 0, stream>>>(nullptr, Wb, ws + OFF_C, ws + OFF_FORM,
                                  1024, 512, 2, 1024, 512, 2, 0);
  // gate path: pre_h = c @ W1 + b1
  k_gemv<<<288, 256, 0, stream>>>(ws + OFF_C, W1, ws + OFF_H, nullptr,
                                  1024, 512, 2, 512, 0, 0, 0);
  // synthesis path: pre_hs = c @ Ws1 + bs1
  k_gemv<<<576, 256, 0, stream>>>(ws + OFF_C, Ws1, ws + OFF_HS, nullptr,
                                  1024, 1024, 4, 1024, 0, 0, 0);
  k_strength<<<36, 256, 0, stream>>>(ws + OFF_H, W2, b2, ws + OFF_STR);
  // insight_pre = gelu(pre_hs) @ Ws2 + bs2
  k_gemv<<<576, 256, 0, stream>>>(ws + OFF_HS, Ws2, ws + OFF_INS, nullptr,
                                  1024, 1024, 4, 1024, 0, 0, 1);
  k_combine<<<1, 64, 0, stream>>>(ws + OFF_STR, ws, out + (size_t)cB*cT*cD);
  k_totln<<<4, 256, 0, stream>>>(ws + OFF_INS, ws + OFF_STR, ws + OFF_MASK, pg,
                                 ws + OFF_CNT, gamma, beta, ws + OFF_NORMED);
  k_proj<<<32, 256, 0, stream>>>(ws + OFF_NORMED, outW, ws + OFF_ADD);
  k_final<<<2048, 256, 0, stream>>>(bridge, ws + OFF_ADD, ws + OFF_CNT, agate, out);
}